// Round 6
// baseline (514.164 us; speedup 1.0000x reference)
//
#include <hip/hip_runtime.h>

typedef __bf16 bf16;
typedef __attribute__((ext_vector_type(4))) __bf16 bf16x4;
typedef __attribute__((ext_vector_type(8))) __bf16 bf16x8;
typedef __attribute__((ext_vector_type(4))) float f32x4;

#define LDS16(gp, lp)                                                          \
  __builtin_amdgcn_global_load_lds(                                            \
      (const __attribute__((address_space(1))) void*)(gp),                     \
      (__attribute__((address_space(3))) void*)(lp), 16, 0, 0)

// ---------------------------------------------------------------------------
// Fused prologue: cast x -> bf16 (blocks 0..8191), cast g1w -> bf16
// (blocks 8192..8319), zero ghsum (block 8320).
__global__ __launch_bounds__(256) void prep_kernel(const float* __restrict__ x,
                                                   const float* __restrict__ g1w,
                                                   bf16* __restrict__ x_bf,
                                                   bf16* __restrict__ g1w_bf,
                                                   float* __restrict__ ghsum) {
  const int bid = blockIdx.x;
  if (bid < 8320) {
    const float* src = bid < 8192 ? x : g1w;
    bf16* dst = bid < 8192 ? x_bf : g1w_bf;
    const int base = bid < 8192 ? bid : bid - 8192;
    int i = (base * 256 + threadIdx.x) * 8;
    float4 a = *(const float4*)(src + i);
    float4 b = *(const float4*)(src + i + 4);
    bf16x8 v;
    v[0] = (bf16)a.x; v[1] = (bf16)a.y; v[2] = (bf16)a.z; v[3] = (bf16)a.w;
    v[4] = (bf16)b.x; v[5] = (bf16)b.y; v[6] = (bf16)b.z; v[7] = (bf16)b.w;
    *(bf16x8*)(dst + i) = v;
  } else {
    float4 z = make_float4(0.f, 0.f, 0.f, 0.f);
    float* p = ghsum + threadIdx.x * 16;
#pragma unroll
    for (int k = 0; k < 4; ++k) *(float4*)(p + k * 4) = z;
  }
}

// ---------------------------------------------------------------------------
// 128x128-tile bf16 MFMA GEMM, C = A(MxK) * B(NxK)^T with per-sample B.
// 4 waves (2M x 2N), per-wave output 64x64 (acc[4][4], ~130 VGPR). BK=32,
// double-buffered 32 KiB LDS, ONE __syncthreads per K-tile, stage(t+1)
// issued before compute(t). __launch_bounds__(256,3) -> 3 blocks/CU.
// RATIONALE (r3-r5 ablation): with one 8-wave block/CU, every schedule
// variant (depth-1, depth-3 counted vmcnt, 2-phase+setprio) lands at
// 663-687 TF because barriers lockstep all waves -- the CU's LDS window and
// MFMA window serialize. Fix: block-level concurrency (m114/m97: 3
// independent blocks/CU overlap one block's barrier drain with the others'
// MFMA). m103 measured 912 TF at this exact occupancy point.
// LDS swizzle (verified, conflicts=0): physical 8-elem chunk p of row r
// holds logical chunk p ^ ((r>>1)&3), applied by permuting the per-lane
// GLOBAL source address (global_load_lds LDS dest stays linear); ds_read
// compensates with qa = q ^ ((lr>>1)&3).
// XCD pinning (T1, verified -40% FETCH): sample = bid&7 -> all of a
// sample's blocks share one XCD; its B panel (<=2 MB) stays L2-resident.
// MODE 0: gate  -> relu(C + bias[col]) column-sums atomically into fout[b*512+col]
// MODE 1: FFN1  -> h = relu(C + bias[b,col]) bf16, coalesced via LDS transpose
// MODE 2: FFN2  -> out = C + bias[b,col] + resid[row,col] stored f32
template <int MODE, int NT>
__global__ __launch_bounds__(256, 3) void gemm128(const bf16* __restrict__ A,
                                                  const bf16* __restrict__ B0, long bstride,
                                                  const float* __restrict__ bias, long biasStride,
                                                  const float* __restrict__ resid,
                                                  float* __restrict__ fout,
                                                  bf16* __restrict__ hout) {
  constexpr int K = NT * 32;
  __shared__ __align__(16) bf16 smem[2 * 8192];  // 2 bufs x (A 128x32 + B 128x32)
  const int tid = threadIdx.x;
  const int lane = tid & 63, wv = tid >> 6;  // 4 waves
  const int wm = wv >> 1, wn = wv & 1;       // 2 (M) x 2 (N)
  const int lr = lane & 15, q = lane >> 4;
  const int bid = blockIdx.x;
  const int b = bid & 7;       // sample -> XCD (dispatch round-robin)
  const int r = bid >> 3;
  const int mb = r & 31;       // 32 M-blocks per sample, fastest (B-panel share)
  const int nb = r >> 5;
  const long blockM = (long)b * 4096 + (long)mb * 128;
  const int blockN = nb * 128;
  const bf16* Ab = A + blockM * K;
  const bf16* Bb = B0 + (long)b * bstride + (long)blockN * K;

  // staging: group g = 16 rows x 4 chunks of 8 bf16; lane l -> row l>>2,
  // physical chunk l&3 <- logical chunk (l&3) ^ key(row), key(s)=(s>>1)&3
  const int s4 = lane >> 2;
  const int cch = ((lane & 3) ^ ((s4 >> 1) & 3)) * 8;
  const int gA0 = wv * 2;  // this wave's two 16-row groups (A and B alike)
  // ds-read swizzle compensation: logical chunk q at row lr -> physical q^key(lr)
  const int qa = q ^ ((lr >> 1) & 3);
  const int aoff = (wm * 64 + lr) * 32 + qa * 8;
  const int boff = (wn * 64 + lr) * 32 + qa * 8;

  f32x4 acc[4][4] = {};

  auto stage = [&](int t) {
    bf16* As = smem + (t & 1) * 8192;
    bf16* Bs = As + 4096;
    const long k0 = (long)t * 32;
#pragma unroll
    for (int li = 0; li < 2; ++li) {
      const int g = gA0 + li;
      LDS16(Ab + (long)(g * 16 + s4) * K + k0 + cch, As + g * 512);
      LDS16(Bb + (long)(g * 16 + s4) * K + k0 + cch, Bs + g * 512);
    }
  };

  stage(0);
  __syncthreads();

#pragma unroll 1
  for (int t = 0; t < NT; ++t) {
    if (t + 1 < NT) stage(t + 1);  // next tile's loads fly during compute
    const bf16* As = smem + (t & 1) * 8192;
    const bf16* Bs = As + 4096;
    bf16x8 af[4], bfr[4];
#pragma unroll
    for (int j = 0; j < 4; ++j) bfr[j] = *(const bf16x8*)&Bs[boff + j * 512];
#pragma unroll
    for (int i = 0; i < 4; ++i) af[i] = *(const bf16x8*)&As[aoff + i * 512];
#pragma unroll
    for (int i = 0; i < 4; ++i)
#pragma unroll
      for (int j = 0; j < 4; ++j)
        acc[i][j] = __builtin_amdgcn_mfma_f32_16x16x32_bf16(af[i], bfr[j], acc[i][j], 0, 0, 0);
    __syncthreads();  // drains: buf t free to overwrite, buf t+1 ready
  }

  // Epilogue. C/D layout: col = lane&15, row = (lane>>4)*4 + reg  [m89/m91]
  if (MODE == 0) {
#pragma unroll
    for (int j = 0; j < 4; ++j) {
      const int gc = blockN + wn * 64 + j * 16 + lr;
      const float bv = bias[gc];
      float s = 0.f;
#pragma unroll
      for (int i = 0; i < 4; ++i)
#pragma unroll
        for (int r2 = 0; r2 < 4; ++r2) {
          float v = acc[i][j][r2] + bv;
          s += v > 0.f ? v : 0.f;
        }
      s += __shfl_xor(s, 16);
      s += __shfl_xor(s, 32);
      if (q == 0) atomicAdd(&fout[b * 512 + gc], s);
    }
  } else if (MODE == 1) {
    // relu -> bf16 tile in LDS (row-major 128x128 = 32 KB), coalesced stores
#pragma unroll
    for (int j = 0; j < 4; ++j) {
      const int gc = wn * 64 + j * 16 + lr;
      const float bv = bias[(long)b * biasStride + blockN + gc];
#pragma unroll
      for (int i = 0; i < 4; ++i)
#pragma unroll
        for (int r2 = 0; r2 < 4; ++r2) {
          const int lrow = wm * 64 + i * 16 + q * 4 + r2;
          float v = acc[i][j][r2] + bv;
          smem[lrow * 128 + gc] = (bf16)(v > 0.f ? v : 0.f);
        }
    }
    __syncthreads();
#pragma unroll
    for (int p = 0; p < 8; ++p) {
      const int row = p * 16 + (tid >> 4);
      const int col = (tid & 15) * 8;
      *(bf16x8*)&hout[(blockM + row) * 2048 + blockN + col] =
          *(const bf16x8*)&smem[row * 128 + col];
    }
  } else {
#pragma unroll
    for (int j = 0; j < 4; ++j) {
      const int gc = blockN + wn * 64 + j * 16 + lr;
      const float bv = bias[(long)b * biasStride + gc];
#pragma unroll
      for (int i = 0; i < 4; ++i)
#pragma unroll
        for (int r2 = 0; r2 < 4; ++r2) {
          const long gr = blockM + wm * 64 + i * 16 + q * 4 + r2;
          fout[gr * 512 + gc] = acc[i][j][r2] + bv + resid[gr * 512 + gc];
        }
    }
  }
}

// ---------------------------------------------------------------------------
// Tiny per-launch kernel: g[b,e], merged ln params, merged biases.
__global__ __launch_bounds__(512) void small_kernel(
    const float* __restrict__ ghsum, const float* __restrict__ g2w,
    const float* __restrict__ g2b, const float* __restrict__ lngI,
    const float* __restrict__ lnbI, const float* __restrict__ tvlg,
    const float* __restrict__ tvlb, const float* __restrict__ b1,
    const float* __restrict__ tvb1, const float* __restrict__ b2,
    const float* __restrict__ tvb2, float* __restrict__ g, float* __restrict__ lng,
    float* __restrict__ lnb, float* __restrict__ b1m, float* __restrict__ b2m) {
  __shared__ float gs[64];
  const int t = threadIdx.x;
  if (t < 64) {
    const int b = t >> 3, e = t & 7;
    float s = 0.f;
    for (int h = 0; h < 512; ++h) s += ghsum[b * 512 + h] * g2w[e * 512 + h];
    float gv = s * (1.f / 4096.f) + g2b[e];
    gs[t] = gv;
    g[t] = gv;
  }
  __syncthreads();
  if (t < 512) {
    float lg = lngI[t], lb = lnbI[t], sg = 0.f, sb = 0.f;
    for (int e = 0; e < 8; ++e) { sg += tvlg[e * 512 + t]; sb += tvlb[e * 512 + t]; }
    lng[t] = lg + 0.03f * (sg - 8.f * lg);
    lnb[t] = lb + 0.03f * (sb - 8.f * lb);
  }
  for (int i = t; i < 8 * 2048; i += 512) {
    const int b = i >> 11, f = i & 2047;
    float s = b1[f];
    for (int e = 0; e < 8; ++e) s += gs[b * 8 + e] * tvb1[e * 2048 + f];
    b1m[i] = s;
  }
  for (int i = t; i < 8 * 512; i += 512) {
    const int b = i >> 9, d = i & 511;
    float s = b2[d];
    for (int e = 0; e < 8; ++e) s += gs[b * 8 + e] * tvb2[e * 512 + d];
    b2m[i] = s;
  }
}

// ---------------------------------------------------------------------------
// Merge base + rank-8 task-vector combo into per-sample bf16 weights.
// Vectorized x4: each thread handles 4 consecutive elements, 8 samples.
__global__ __launch_bounds__(256) void merge_kernel(
    const float* __restrict__ W1, const float* __restrict__ tvW1,
    const float* __restrict__ W2, const float* __restrict__ tvW2,
    const float* __restrict__ g, bf16* __restrict__ W1m, bf16* __restrict__ W2m) {
  int idx = (blockIdx.x * 256 + threadIdx.x) * 4;
  const float* Wp;
  const float* tvp;
  bf16* outp;
  if (idx < 1048576) {
    Wp = W1; tvp = tvW1; outp = W1m;
  } else {
    idx -= 1048576;
    Wp = W2; tvp = tvW2; outp = W2m;
  }
  float4 w = *(const float4*)(Wp + idx);
  float4 tv[8];
#pragma unroll
  for (int e = 0; e < 8; ++e) tv[e] = *(const float4*)(tvp + (long)e * 1048576 + idx);
#pragma unroll
  for (int b = 0; b < 8; ++b) {
    float4 s = w;
#pragma unroll
    for (int e = 0; e < 8; ++e) {
      const float ge = g[b * 8 + e];
      s.x += ge * tv[e].x; s.y += ge * tv[e].y;
      s.z += ge * tv[e].z; s.w += ge * tv[e].w;
    }
    bf16x4 o;
    o[0] = (bf16)s.x; o[1] = (bf16)s.y; o[2] = (bf16)s.z; o[3] = (bf16)s.w;
    *(bf16x4*)(outp + (long)b * 1048576 + idx) = o;
  }
}

// ---------------------------------------------------------------------------
// In-place layernorm over D=512, one wave per row.
__global__ __launch_bounds__(256) void ln_kernel(float* __restrict__ out,
                                                 const float* __restrict__ lng,
                                                 const float* __restrict__ lnb) {
  const int wv = threadIdx.x >> 6, lane = threadIdx.x & 63;
  const long row = (long)blockIdx.x * 4 + wv;
  float* p = out + row * 512 + lane * 8;
  float4 a = *(float4*)p;
  float4 b = *(float4*)(p + 4);
  float v[8] = {a.x, a.y, a.z, a.w, b.x, b.y, b.z, b.w};
  float s1 = 0.f, s2 = 0.f;
#pragma unroll
  for (int k = 0; k < 8; ++k) { s1 += v[k]; s2 += v[k] * v[k]; }
#pragma unroll
  for (int off = 32; off > 0; off >>= 1) {
    s1 += __shfl_xor(s1, off);
    s2 += __shfl_xor(s2, off);
  }
  const float mean = s1 * (1.f / 512.f);
  const float var = s2 * (1.f / 512.f) - mean * mean;
  const float rstd = rsqrtf(var + 1e-5f);
  const int c = lane * 8;
  float o[8];
#pragma unroll
  for (int k = 0; k < 8; ++k) o[k] = (v[k] - mean) * rstd * lng[c + k] + lnb[c + k];
  *(float4*)p = make_float4(o[0], o[1], o[2], o[3]);
  *(float4*)(p + 4) = make_float4(o[4], o[5], o[6], o[7]);
}

// ---------------------------------------------------------------------------
extern "C" void kernel_launch(void* const* d_in, const int* in_sizes, int n_in,
                              void* d_out, int out_size, void* d_ws, size_t ws_size,
                              hipStream_t stream) {
  const float* x    = (const float*)d_in[0];
  const float* g1w  = (const float*)d_in[1];
  const float* g1b  = (const float*)d_in[2];
  const float* g2w  = (const float*)d_in[3];
  const float* g2b  = (const float*)d_in[4];
  const float* W1   = (const float*)d_in[5];
  const float* b1   = (const float*)d_in[6];
  const float* W2   = (const float*)d_in[7];
  const float* b2   = (const float*)d_in[8];
  const float* lngI = (const float*)d_in[9];
  const float* lnbI = (const float*)d_in[10];
  const float* tvW1 = (const float*)d_in[11];
  const float* tvb1 = (const float*)d_in[12];
  const float* tvW2 = (const float*)d_in[13];
  const float* tvb2 = (const float*)d_in[14];
  const float* tvlg = (const float*)d_in[15];
  const float* tvlb = (const float*)d_in[16];
  float* out = (float*)d_out;

  char* w = (char*)d_ws;
  bf16*  x_bf   = (bf16*)(w);                   // 33,554,432 B
  bf16*  g1w_bf = (bf16*)(w + 33554432);        //    524,288 B
  bf16*  W1m    = (bf16*)(w + 34078720);        // 16,777,216 B
  bf16*  W2m    = (bf16*)(w + 50855936);        // 16,777,216 B
  bf16*  h      = (bf16*)(w + 67633152);        // 134,217,728 B
  float* ghsum  = (float*)(w + 201850880);      //     16,384 B
  float* g      = (float*)(w + 201867264);      //        256 B
  float* b1m    = (float*)(w + 201867520);      //     65,536 B
  float* b2m    = (float*)(w + 201933056);      //     16,384 B
  float* lng    = (float*)(w + 201949440);      //      2,048 B
  float* lnb    = (float*)(w + 201951488);      //      2,048 B

  // Stage 0: fused casts + zero gate accumulator
  prep_kernel<<<8321, 256, 0, stream>>>(x, g1w, x_bf, g1w_bf, ghsum);
  // Stage 1: gate GEMM + relu column-sum   (per sample: M=4096, N=512, K=512)
  gemm128<0, 16><<<1024, 256, 0, stream>>>(x_bf, g1w_bf, 0, g1b, 0,
                                           nullptr, ghsum, nullptr);
  // Stage 2: g, merged ln params, merged biases
  small_kernel<<<1, 512, 0, stream>>>(ghsum, g2w, g2b, lngI, lnbI, tvlg, tvlb,
                                      b1, tvb1, b2, tvb2, g, lng, lnb, b1m, b2m);
  // Stage 3: per-sample weight merge -> bf16 (x4 vectorized)
  merge_kernel<<<2048, 256, 0, stream>>>(W1, tvW1, W2, tvW2, g, W1m, W2m);
  // Stage 4: h = relu(x @ W1m^T + b1m)     (per sample: M=4096, N=2048, K=512)
  gemm128<1, 16><<<4096, 256, 0, stream>>>(x_bf, W1m, 1048576, b1m, 2048,
                                           nullptr, nullptr, h);
  // Stage 5: out = h @ W2m^T + b2m + x     (per sample: M=4096, N=512, K=2048)
  gemm128<2, 64><<<1024, 256, 0, stream>>>(h, W2m, 1048576, b2m, 512,
                                           x, out, nullptr);
  // Stage 6: in-place layernorm
  ln_kernel<<<8192, 256, 0, stream>>>(out, lng, lnb);
}

// Round 7
// 452.532 us; speedup vs baseline: 1.1362x; 1.1362x over previous
//
#include <hip/hip_runtime.h>

typedef __bf16 bf16;
typedef __attribute__((ext_vector_type(4))) __bf16 bf16x4;
typedef __attribute__((ext_vector_type(8))) __bf16 bf16x8;
typedef __attribute__((ext_vector_type(4))) float f32x4;

#define LDS16(gp, lp)                                                          \
  __builtin_amdgcn_global_load_lds(                                            \
      (const __attribute__((address_space(1))) void*)(gp),                     \
      (__attribute__((address_space(3))) void*)(lp), 16, 0, 0)

// ---------------------------------------------------------------------------
// Fused prologue: cast x -> bf16 (blocks 0..8191), cast g1w -> bf16
// (blocks 8192..8319), zero ghsum (block 8320).
__global__ __launch_bounds__(256) void prep_kernel(const float* __restrict__ x,
                                                   const float* __restrict__ g1w,
                                                   bf16* __restrict__ x_bf,
                                                   bf16* __restrict__ g1w_bf,
                                                   float* __restrict__ ghsum) {
  const int bid = blockIdx.x;
  if (bid < 8320) {
    const float* src = bid < 8192 ? x : g1w;
    bf16* dst = bid < 8192 ? x_bf : g1w_bf;
    const int base = bid < 8192 ? bid : bid - 8192;
    int i = (base * 256 + threadIdx.x) * 8;
    float4 a = *(const float4*)(src + i);
    float4 b = *(const float4*)(src + i + 4);
    bf16x8 v;
    v[0] = (bf16)a.x; v[1] = (bf16)a.y; v[2] = (bf16)a.z; v[3] = (bf16)a.w;
    v[4] = (bf16)b.x; v[5] = (bf16)b.y; v[6] = (bf16)b.z; v[7] = (bf16)b.w;
    *(bf16x8*)(dst + i) = v;
  } else {
    float4 z = make_float4(0.f, 0.f, 0.f, 0.f);
    float* p = ghsum + threadIdx.x * 16;
#pragma unroll
    for (int k = 0; k < 4; ++k) *(float4*)(p + k * 4) = z;
  }
}

// ---------------------------------------------------------------------------
// 256x256-tile bf16 MFMA GEMM, C = A(MxK) * B(NxK)^T with per-sample B.
// 8 waves (2M x 4N), per-wave output 128x64. BK=64: each loop iteration
// stages ONE 64-deep K-tile (as two BK=32 sub-slices, 8 gloads/thread) into
// the other half of a 128 KiB double buffer, computes 64 MFMA/wave (2 sub-
// slices x 32), then ONE __syncthreads. Rationale (r3-r6 ablation): per-
// barrier fixed overhead ~2500cy dominates (MFMA-busy only ~930cy/tile at
// BK=32); depth-3 counted vmcnt and phase-split+setprio both null; 128-tile
// x 3 blocks/CU regressed (417 TF). Halving barrier count amortizes the
// fixed cost 2x. NT counts BK=64 tiles.
// LDS swizzle (verified, conflicts=0): physical 8-elem chunk p of row r
// holds logical chunk p ^ ((r>>1)&3), applied by permuting the per-lane
// GLOBAL source address (global_load_lds LDS dest stays linear); ds_read
// compensates with qa = q ^ ((lr>>1)&3).
// XCD pinning (T1, verified -40% FETCH): sample = bid&7 -> all of a
// sample's blocks share one XCD; its B panel stays L2-resident.
// MODE 0: gate  -> relu(C + bias[col]) column-sums atomically into fout[b*512+col]
// MODE 1: FFN1  -> h = relu(C + bias[b,col]) bf16, coalesced via LDS transpose
// MODE 2: FFN2  -> out = C + bias[b,col] + resid[row,col] stored f32
template <int MODE, int NT>
__global__ __launch_bounds__(512) void gemm256(const bf16* __restrict__ A,
                                               const bf16* __restrict__ B0, long bstride,
                                               const float* __restrict__ bias, long biasStride,
                                               const float* __restrict__ resid,
                                               float* __restrict__ fout,
                                               bf16* __restrict__ hout) {
  constexpr int K = NT * 64;
  // 2 bufs x 2 sub-slices x (A 256x32 + B 256x32) = 128 KiB
  __shared__ __align__(16) bf16 smem[2 * 32768];
  const int tid = threadIdx.x;
  const int lane = tid & 63, wv = tid >> 6;  // 8 waves
  const int wm = wv >> 2, wn = wv & 3;       // 2 (M) x 4 (N)
  const int lr = lane & 15, q = lane >> 4;
  const int bid = blockIdx.x;
  const int b = bid & 7;  // sample -> XCD (dispatch round-robin)
  const int r = bid >> 3;
  const int mb = r & 15;  // 16 M-blocks per sample, fastest (B-panel share)
  const int nb = r >> 4;
  const long blockM = (long)b * 4096 + (long)mb * 256;
  const int blockN = nb * 256;
  const bf16* Ab = A + blockM * K;
  const bf16* Bb = B0 + (long)b * bstride + (long)blockN * K;

  // staging: group g = 16 rows x 4 chunks of 8 bf16; lane l -> row l>>2,
  // physical chunk l&3 <- logical chunk (l&3) ^ key(row), key(s)=(s>>1)&3
  const int s4 = lane >> 2;
  const int cch = ((lane & 3) ^ ((s4 >> 1) & 3)) * 8;
  const int gA0 = wv * 2;  // this wave's two 16-row groups (A and B alike)
  // ds-read swizzle compensation: logical chunk q at row lr -> physical q^key(lr)
  const int qa = q ^ ((lr >> 1) & 3);
  const int aoff = (wm * 128 + lr) * 32 + qa * 8;
  const int boff = (wn * 64 + lr) * 32 + qa * 8;

  f32x4 acc[8][4] = {};

  auto stage = [&](int t) {
    bf16* buf = smem + (t & 1) * 32768;
    const long k0 = (long)t * 64;
#pragma unroll
    for (int s = 0; s < 2; ++s) {  // two BK=32 sub-slices
      bf16* As = buf + s * 16384;
      bf16* Bs = As + 8192;
      const long kk = k0 + s * 32;
#pragma unroll
      for (int li = 0; li < 2; ++li) {
        const int g = gA0 + li;
        LDS16(Ab + (long)(g * 16 + s4) * K + kk + cch, As + g * 512);
        LDS16(Bb + (long)(g * 16 + s4) * K + kk + cch, Bs + g * 512);
      }
    }
  };

  stage(0);
  __syncthreads();

#pragma unroll 1
  for (int t = 0; t < NT; ++t) {
    if (t + 1 < NT) stage(t + 1);  // 8 loads/thread fly during compute
    const bf16* buf = smem + (t & 1) * 32768;
#pragma unroll
    for (int s = 0; s < 2; ++s) {
      const bf16* As = buf + s * 16384;
      const bf16* Bs = As + 8192;
      bf16x8 af[8], bfr[4];
#pragma unroll
      for (int j = 0; j < 4; ++j) bfr[j] = *(const bf16x8*)&Bs[boff + j * 512];
#pragma unroll
      for (int i = 0; i < 8; ++i) af[i] = *(const bf16x8*)&As[aoff + i * 512];
#pragma unroll
      for (int i = 0; i < 8; ++i)
#pragma unroll
        for (int j = 0; j < 4; ++j)
          acc[i][j] = __builtin_amdgcn_mfma_f32_16x16x32_bf16(af[i], bfr[j], acc[i][j], 0, 0, 0);
    }
    __syncthreads();  // drains: buf t free to overwrite, buf t+1 ready
  }

  // Epilogue. C/D layout: col = lane&15, row = (lane>>4)*4 + reg  [m89/m91]
  if (MODE == 0) {
#pragma unroll
    for (int j = 0; j < 4; ++j) {
      const int gc = blockN + wn * 64 + j * 16 + lr;
      const float bv = bias[gc];
      float s = 0.f;
#pragma unroll
      for (int i = 0; i < 8; ++i)
#pragma unroll
        for (int r2 = 0; r2 < 4; ++r2) {
          float v = acc[i][j][r2] + bv;
          s += v > 0.f ? v : 0.f;
        }
      s += __shfl_xor(s, 16);
      s += __shfl_xor(s, 32);
      if (q == 0) atomicAdd(&fout[b * 512 + gc], s);
    }
  } else if (MODE == 1) {
    // relu -> bf16, two 128-row halves staged through LDS for coalesced stores
    float bvv[4];
#pragma unroll
    for (int j = 0; j < 4; ++j)
      bvv[j] = bias[(long)b * biasStride + blockN + wn * 64 + j * 16 + lr];
#pragma unroll 1
    for (int half = 0; half < 2; ++half) {
      __syncthreads();
      if (wm == half) {
#pragma unroll
        for (int i = 0; i < 8; ++i)
#pragma unroll
          for (int j = 0; j < 4; ++j)
#pragma unroll
            for (int r2 = 0; r2 < 4; ++r2) {
              const int row = i * 16 + q * 4 + r2;
              const int col = wn * 64 + j * 16 + lr;
              float v = acc[i][j][r2] + bvv[j];
              smem[row * 256 + col] = (bf16)(v > 0.f ? v : 0.f);
            }
      }
      __syncthreads();
#pragma unroll
      for (int p = 0; p < 8; ++p) {
        const int row = p * 16 + (tid >> 5);
        const int seg = tid & 31;
        *(bf16x8*)&hout[(blockM + half * 128 + row) * 2048 + blockN + seg * 8] =
            *(const bf16x8*)&smem[row * 256 + seg * 8];
      }
    }
  } else {
#pragma unroll
    for (int j = 0; j < 4; ++j) {
      const int gc = blockN + wn * 64 + j * 16 + lr;
      const float bv = bias[(long)b * biasStride + gc];
#pragma unroll
      for (int i = 0; i < 8; ++i)
#pragma unroll
        for (int r2 = 0; r2 < 4; ++r2) {
          const long gr = blockM + wm * 128 + i * 16 + q * 4 + r2;
          fout[gr * 512 + gc] = acc[i][j][r2] + bv + resid[gr * 512 + gc];
        }
    }
  }
}

// ---------------------------------------------------------------------------
// Tiny per-launch kernel: g[b,e], merged ln params, merged biases.
__global__ __launch_bounds__(512) void small_kernel(
    const float* __restrict__ ghsum, const float* __restrict__ g2w,
    const float* __restrict__ g2b, const float* __restrict__ lngI,
    const float* __restrict__ lnbI, const float* __restrict__ tvlg,
    const float* __restrict__ tvlb, const float* __restrict__ b1,
    const float* __restrict__ tvb1, const float* __restrict__ b2,
    const float* __restrict__ tvb2, float* __restrict__ g, float* __restrict__ lng,
    float* __restrict__ lnb, float* __restrict__ b1m, float* __restrict__ b2m) {
  __shared__ float gs[64];
  const int t = threadIdx.x;
  if (t < 64) {
    const int b = t >> 3, e = t & 7;
    float s = 0.f;
    for (int h = 0; h < 512; ++h) s += ghsum[b * 512 + h] * g2w[e * 512 + h];
    float gv = s * (1.f / 4096.f) + g2b[e];
    gs[t] = gv;
    g[t] = gv;
  }
  __syncthreads();
  if (t < 512) {
    float lg = lngI[t], lb = lnbI[t], sg = 0.f, sb = 0.f;
    for (int e = 0; e < 8; ++e) { sg += tvlg[e * 512 + t]; sb += tvlb[e * 512 + t]; }
    lng[t] = lg + 0.03f * (sg - 8.f * lg);
    lnb[t] = lb + 0.03f * (sb - 8.f * lb);
  }
  for (int i = t; i < 8 * 2048; i += 512) {
    const int b = i >> 11, f = i & 2047;
    float s = b1[f];
    for (int e = 0; e < 8; ++e) s += gs[b * 8 + e] * tvb1[e * 2048 + f];
    b1m[i] = s;
  }
  for (int i = t; i < 8 * 512; i += 512) {
    const int b = i >> 9, d = i & 511;
    float s = b2[d];
    for (int e = 0; e < 8; ++e) s += gs[b * 8 + e] * tvb2[e * 512 + d];
    b2m[i] = s;
  }
}

// ---------------------------------------------------------------------------
// Merge base + rank-8 task-vector combo into per-sample bf16 weights.
// Vectorized x4: each thread handles 4 consecutive elements, 8 samples.
__global__ __launch_bounds__(256) void merge_kernel(
    const float* __restrict__ W1, const float* __restrict__ tvW1,
    const float* __restrict__ W2, const float* __restrict__ tvW2,
    const float* __restrict__ g, bf16* __restrict__ W1m, bf16* __restrict__ W2m) {
  int idx = (blockIdx.x * 256 + threadIdx.x) * 4;
  const float* Wp;
  const float* tvp;
  bf16* outp;
  if (idx < 1048576) {
    Wp = W1; tvp = tvW1; outp = W1m;
  } else {
    idx -= 1048576;
    Wp = W2; tvp = tvW2; outp = W2m;
  }
  float4 w = *(const float4*)(Wp + idx);
  float4 tv[8];
#pragma unroll
  for (int e = 0; e < 8; ++e) tv[e] = *(const float4*)(tvp + (long)e * 1048576 + idx);
#pragma unroll
  for (int b = 0; b < 8; ++b) {
    float4 s = w;
#pragma unroll
    for (int e = 0; e < 8; ++e) {
      const float ge = g[b * 8 + e];
      s.x += ge * tv[e].x; s.y += ge * tv[e].y;
      s.z += ge * tv[e].z; s.w += ge * tv[e].w;
    }
    bf16x4 o;
    o[0] = (bf16)s.x; o[1] = (bf16)s.y; o[2] = (bf16)s.z; o[3] = (bf16)s.w;
    *(bf16x4*)(outp + (long)b * 1048576 + idx) = o;
  }
}

// ---------------------------------------------------------------------------
// In-place layernorm over D=512, one wave per row.
__global__ __launch_bounds__(256) void ln_kernel(float* __restrict__ out,
                                                 const float* __restrict__ lng,
                                                 const float* __restrict__ lnb) {
  const int wv = threadIdx.x >> 6, lane = threadIdx.x & 63;
  const long row = (long)blockIdx.x * 4 + wv;
  float* p = out + row * 512 + lane * 8;
  float4 a = *(float4*)p;
  float4 b = *(float4*)(p + 4);
  float v[8] = {a.x, a.y, a.z, a.w, b.x, b.y, b.z, b.w};
  float s1 = 0.f, s2 = 0.f;
#pragma unroll
  for (int k = 0; k < 8; ++k) { s1 += v[k]; s2 += v[k] * v[k]; }
#pragma unroll
  for (int off = 32; off > 0; off >>= 1) {
    s1 += __shfl_xor(s1, off);
    s2 += __shfl_xor(s2, off);
  }
  const float mean = s1 * (1.f / 512.f);
  const float var = s2 * (1.f / 512.f) - mean * mean;
  const float rstd = rsqrtf(var + 1e-5f);
  const int c = lane * 8;
  float o[8];
#pragma unroll
  for (int k = 0; k < 8; ++k) o[k] = (v[k] - mean) * rstd * lng[c + k] + lnb[c + k];
  *(float4*)p = make_float4(o[0], o[1], o[2], o[3]);
  *(float4*)(p + 4) = make_float4(o[4], o[5], o[6], o[7]);
}

// ---------------------------------------------------------------------------
extern "C" void kernel_launch(void* const* d_in, const int* in_sizes, int n_in,
                              void* d_out, int out_size, void* d_ws, size_t ws_size,
                              hipStream_t stream) {
  const float* x    = (const float*)d_in[0];
  const float* g1w  = (const float*)d_in[1];
  const float* g1b  = (const float*)d_in[2];
  const float* g2w  = (const float*)d_in[3];
  const float* g2b  = (const float*)d_in[4];
  const float* W1   = (const float*)d_in[5];
  const float* b1   = (const float*)d_in[6];
  const float* W2   = (const float*)d_in[7];
  const float* b2   = (const float*)d_in[8];
  const float* lngI = (const float*)d_in[9];
  const float* lnbI = (const float*)d_in[10];
  const float* tvW1 = (const float*)d_in[11];
  const float* tvb1 = (const float*)d_in[12];
  const float* tvW2 = (const float*)d_in[13];
  const float* tvb2 = (const float*)d_in[14];
  const float* tvlg = (const float*)d_in[15];
  const float* tvlb = (const float*)d_in[16];
  float* out = (float*)d_out;

  char* w = (char*)d_ws;
  bf16*  x_bf   = (bf16*)(w);                   // 33,554,432 B
  bf16*  g1w_bf = (bf16*)(w + 33554432);        //    524,288 B
  bf16*  W1m    = (bf16*)(w + 34078720);        // 16,777,216 B
  bf16*  W2m    = (bf16*)(w + 50855936);        // 16,777,216 B
  bf16*  h      = (bf16*)(w + 67633152);        // 134,217,728 B
  float* ghsum  = (float*)(w + 201850880);      //     16,384 B
  float* g      = (float*)(w + 201867264);      //        256 B
  float* b1m    = (float*)(w + 201867520);      //     65,536 B
  float* b2m    = (float*)(w + 201933056);      //     16,384 B
  float* lng    = (float*)(w + 201949440);      //      2,048 B
  float* lnb    = (float*)(w + 201951488);      //      2,048 B

  // Stage 0: fused casts + zero gate accumulator
  prep_kernel<<<8321, 256, 0, stream>>>(x, g1w, x_bf, g1w_bf, ghsum);
  // Stage 1: gate GEMM + relu column-sum   (per sample: M=4096, N=512, K=512)
  gemm256<0, 8><<<256, 512, 0, stream>>>(x_bf, g1w_bf, 0, g1b, 0,
                                         nullptr, ghsum, nullptr);
  // Stage 2: g, merged ln params, merged biases
  small_kernel<<<1, 512, 0, stream>>>(ghsum, g2w, g2b, lngI, lnbI, tvlg, tvlb,
                                      b1, tvb1, b2, tvb2, g, lng, lnb, b1m, b2m);
  // Stage 3: per-sample weight merge -> bf16 (x4 vectorized)
  merge_kernel<<<2048, 256, 0, stream>>>(W1, tvW1, W2, tvW2, g, W1m, W2m);
  // Stage 4: h = relu(x @ W1m^T + b1m)     (per sample: M=4096, N=2048, K=512)
  gemm256<1, 8><<<1024, 512, 0, stream>>>(x_bf, W1m, 1048576, b1m, 2048,
                                          nullptr, nullptr, h);
  // Stage 5: out = h @ W2m^T + b2m + x     (per sample: M=4096, N=512, K=2048)
  gemm256<2, 32><<<256, 512, 0, stream>>>(h, W2m, 1048576, b2m, 512,
                                          x, out, nullptr);
  // Stage 6: in-place layernorm
  ln_kernel<<<8192, 256, 0, stream>>>(out, lng, lnb);
}